// Round 1
// baseline (216.908 us; speedup 1.0000x reference)
//
#include <hip/hip_runtime.h>
#include <hip/hip_cooperative_groups.h>

namespace cg = cooperative_groups;

// Problem: output = embeddings[unseen_index] (200 floats). Only edges with
// edge_dst == unseen_index contribute (~E/N = 8 of 400000 expected).
//
// Round 3: fuse memset + filter + compute + finalize into ONE cooperative
// kernel (grid.sync between phases). Rationale (rocprof): top-5 dispatches
// are all the 48-us harness ws-poison fill; our controllable cost is the
// 4 graph nodes (~15-18 us incl. node gaps). Fusion removes 3 nodes + the
// zero-memset (per-block private filter slots are written unconditionally,
// so no pre-zeroed global atomic counter is needed).
//
// Phase 1: each block scans its slice of edge_dst (int4 loads) into a
//          private LDS list, then writes its own count+list to ws slots.
//          Block 0 additionally zeroes the 200-float accumulator.
// grid.sync()
// Phase 2: every block loads the 256 per-block counts (1 load/thread,
//          parallel), thread 0 flattens the ~8 matches from LDS counts
//          (global list reads only for non-empty blocks). Block b handles
//          i-chunk (b&7) and j-slots (b>>3, stride 32), accumulates the
//          basis-decomposed message partials, atomicAdds into acc.
// grid.sync()
// Phase 3: block 0 writes out = acc / max(true_count, 1).

#define DE 200
#define IN_DIM 400
#define ICHUNK 50          // IN_DIM / NCHUNK
#define NCHUNK 8
#define GBLOCKS 256
#define JSLOTS (GBLOCKS / NCHUNK)   // 32
#define PBCAP 64           // per-block match cap (expected matches/block ~0.03)
#define MAXE 128           // flattened match cap (expected total ~8)

// ws layout (32-bit words):
// [0 .. 256)                per-block true counts (always written)
// [256 .. 256+256*PBCAP)    per-block match lists
// [20480 .. 20680)          acc floats (zeroed by block 0 in phase 1)
#define WS_CNT_OFF  0
#define WS_LIST_OFF 256
#define WS_ACC_OFF  20480

__global__ __launch_bounds__(256, 2)
void fused_k(const float* __restrict__ Eemb,
             const float* __restrict__ Remb,
             const float* __restrict__ basis,
             const float* __restrict__ att,
             const int* __restrict__ node_id,
             const int* __restrict__ edge_src,
             const int* __restrict__ edge_dst,
             const int* __restrict__ edge_type,
             const int* __restrict__ rel_index,
             const int* __restrict__ unseen,
             int n_edges,
             int* __restrict__ ws,
             float* __restrict__ out)
{
    const int b = blockIdx.x;
    const int t = threadIdx.x;

    int*   g_cnt  = ws + WS_CNT_OFF;
    int*   g_list = ws + WS_LIST_OFF;
    float* acc    = (float*)ws + WS_ACC_OFF;

    __shared__ int   s_cnt;
    __shared__ int   s_list[PBCAP];
    __shared__ int   s_counts[GBLOCKS];
    __shared__ int   s_edges[MAXE];
    __shared__ int   s_total, s_listed;
    __shared__ float s_xj[ICHUNK];

    // ---------------- Phase 1: private filter ----------------
    if (t == 0) s_cnt = 0;
    __syncthreads();

    const int u  = unseen[0];
    const int n4 = n_edges >> 2;
    const int4* edge_dst4 = (const int4*)edge_dst;
    for (int idx = b * blockDim.x + t; idx < n4; idx += GBLOCKS * blockDim.x) {
        const int4 v = edge_dst4[idx];
        const int  e = idx * 4;
        if (v.x == u) { int p = atomicAdd(&s_cnt, 1); if (p < PBCAP) s_list[p] = e;     }
        if (v.y == u) { int p = atomicAdd(&s_cnt, 1); if (p < PBCAP) s_list[p] = e + 1; }
        if (v.z == u) { int p = atomicAdd(&s_cnt, 1); if (p < PBCAP) s_list[p] = e + 2; }
        if (v.w == u) { int p = atomicAdd(&s_cnt, 1); if (p < PBCAP) s_list[p] = e + 3; }
    }
    if (b == 0) {
        if (t < (n_edges & 3)) {
            const int e = n4 * 4 + t;
            if (edge_dst[e] == u) { int p = atomicAdd(&s_cnt, 1); if (p < PBCAP) s_list[p] = e; }
        }
        if (t < DE) acc[t] = 0.f;   // zero accumulator (ws is 0xAA-poisoned)
    }
    __syncthreads();
    if (t == 0) g_cnt[b] = s_cnt;   // true count, written unconditionally
    {
        const int cl = s_cnt < PBCAP ? s_cnt : PBCAP;
        if (t < cl) g_list[b * PBCAP + t] = s_list[t];
    }

    cg::this_grid().sync();

    // ---------------- Phase 2: flatten + compute ----------------
    // parallel load of all per-block counts (avoid serial L2-latency chain)
    s_counts[t] = g_cnt[t];        // blockDim.x == GBLOCKS == 256
    __syncthreads();
    if (t == 0) {
        int tot = 0, listed = 0;
        for (int bb = 0; bb < GBLOCKS; ++bb) {
            const int c  = s_counts[bb];
            tot += c;
            const int cl = c < PBCAP ? c : PBCAP;
            for (int k = 0; k < cl && listed < MAXE; ++k)
                s_edges[listed++] = g_list[bb * PBCAP + k];
        }
        s_total  = tot;
        s_listed = listed;
    }
    __syncthreads();

    const int cnt   = s_listed;
    const int chunk = b & (NCHUNK - 1);
    const int base  = chunk * ICHUNK;
    const int jslot = b >> 3;              // 0..31

    float m = 0.f;
    bool any = false;
    for (int j = jslot; j < cnt; j += JSLOTS) {
        const int e   = s_edges[j];
        const int src = edge_src[e];
        const int typ = edge_type[e];
        const int ri  = rel_index[e];
        __syncthreads();                   // protect s_xj from prior-iter readers
        if (t < ICHUNK) {
            const int i = base + t;
            s_xj[t] = (i < DE) ? Eemb[(size_t)node_id[src] * DE + i]
                               : Remb[(size_t)ri * DE + (i - DE)];
        }
        __syncthreads();
        if (t < DE) {
            const float a0 = att[typ * 4 + 0];
            const float a1 = att[typ * 4 + 1];
            const float a2 = att[typ * 4 + 2];
            const float a3 = att[typ * 4 + 3];
            float h0 = 0.f, h1 = 0.f, h2 = 0.f, h3 = 0.f;
            // basis[b][i][o] at (b*IN_DIM + i)*DE + o ; b-stride = 80000
            #pragma unroll 5
            for (int ii = 0; ii < ICHUNK; ++ii) {
                const float xv  = s_xj[ii];
                const int   off = (base + ii) * DE + t;
                h0 += xv * basis[off];
                h1 += xv * basis[off + 80000];
                h2 += xv * basis[off + 160000];
                h3 += xv * basis[off + 240000];
            }
            m += a0 * h0 + a1 * h1 + a2 * h2 + a3 * h3;
            any = true;
        }
    }
    if (any) atomicAdd(&acc[t], m);

    cg::this_grid().sync();

    // ---------------- Phase 3: finalize ----------------
    if (b == 0 && t < DE) {
        int c = s_total;
        if (c < 1) c = 1;
        out[t] = acc[t] / (float)c;
    }
}

extern "C" void kernel_launch(void* const* d_in, const int* in_sizes, int n_in,
                              void* d_out, int out_size, void* d_ws, size_t ws_size,
                              hipStream_t stream) {
    const float* Eemb  = (const float*)d_in[0];
    const float* Remb  = (const float*)d_in[1];
    const float* basis = (const float*)d_in[2];
    const float* att   = (const float*)d_in[3];
    const int* node_id  = (const int*)d_in[4];
    const int* edge_src = (const int*)d_in[5];
    const int* edge_dst = (const int*)d_in[6];
    const int* edge_typ = (const int*)d_in[7];
    const int* rel_idx  = (const int*)d_in[8];
    const int* unseen   = (const int*)d_in[9];
    float* out = (float*)d_out;
    int*   ws  = (int*)d_ws;

    int n_edges = in_sizes[6];

    void* args[] = {
        (void*)&Eemb, (void*)&Remb, (void*)&basis, (void*)&att,
        (void*)&node_id, (void*)&edge_src, (void*)&edge_dst,
        (void*)&edge_typ, (void*)&rel_idx, (void*)&unseen,
        (void*)&n_edges, (void*)&ws, (void*)&out
    };
    hipLaunchCooperativeKernel((void*)fused_k, dim3(GBLOCKS), dim3(256),
                               args, 0, stream);
}

// Round 2
// 144.687 us; speedup vs baseline: 1.4992x; 1.4992x over previous
//
#include <hip/hip_runtime.h>

// Problem: output = embeddings[unseen_index] (200 floats). Only edges with
// edge_dst == unseen_index contribute (~E/N = 8 of 400000 expected).
//
// Round 4: round-1's cooperative grid.sync cost ~35 us per sync (72 us
// kernel at 0.8% VALUBusy) -- kernel boundaries are the cheaper barrier.
// Keep 2 dispatches (was 4 in the 131.7-us baseline):
//   filter_k : per-block private filter. Writes its own count slot
//              UNCONDITIONALLY (no pre-zeroed global counter -> no memset
//              node). Block 0 also zeroes acc[200] and the done counter.
//   compute_k: each block flattens the ~8 matches (parallel count load +
//              ballot, thread 0 walks set bits), computes its
//              (i-chunk, edge-slot) partial from basis, atomicAdds into
//              acc. Last block (done-counter pattern, device-scope
//              atomics are XCD-coherent) divides by count and writes out
//              -> no finalize node.

#define DE 200
#define IN_DIM 400
#define ICHUNK 50          // IN_DIM / NCHUNK
#define NCHUNK 8
#define MAXJ 32
#define FBLOCKS 256        // filter grid; compute reads exactly this many counts
#define TOTB (NCHUNK * MAXJ)   // 256 compute blocks
#define PBCAP 64           // per-filter-block match cap (expected ~0.03)
#define MAXE 128           // flattened match cap (expected total ~8)

// ws layout (32-bit words):
// [0 .. 256)        per-filter-block true counts (always written)
// [256]             done counter (zeroed by filter block 0)
// [320 .. 520)      acc floats   (zeroed by filter block 0)
// [1024 .. )        per-block match lists, PBCAP each
#define WS_CNT_OFF   0
#define WS_DONE_OFF  256
#define WS_ACC_OFF   320
#define WS_LIST_OFF  1024

__global__ __launch_bounds__(256)
void filter_k(const int4* __restrict__ edge_dst4,
              const int* __restrict__ edge_dst,
              const int* __restrict__ unseen,
              int n4, int n_edges,
              int* __restrict__ ws) {
    const int b = blockIdx.x;
    const int t = threadIdx.x;
    __shared__ int s_cnt;
    __shared__ int s_list[PBCAP];
    if (t == 0) s_cnt = 0;
    __syncthreads();

    const int u = unseen[0];
    for (int idx = b * blockDim.x + t; idx < n4; idx += FBLOCKS * blockDim.x) {
        const int4 v = edge_dst4[idx];
        const int  e = idx * 4;
        if (v.x == u) { int p = atomicAdd(&s_cnt, 1); if (p < PBCAP) s_list[p] = e;     }
        if (v.y == u) { int p = atomicAdd(&s_cnt, 1); if (p < PBCAP) s_list[p] = e + 1; }
        if (v.z == u) { int p = atomicAdd(&s_cnt, 1); if (p < PBCAP) s_list[p] = e + 2; }
        if (v.w == u) { int p = atomicAdd(&s_cnt, 1); if (p < PBCAP) s_list[p] = e + 3; }
    }
    if (b == 0) {
        if (t < (n_edges & 3)) {
            const int e = n4 * 4 + t;
            if (edge_dst[e] == u) { int p = atomicAdd(&s_cnt, 1); if (p < PBCAP) s_list[p] = e; }
        }
        // zero accumulator + done counter (ws is 0xAA-poisoned each launch)
        if (t < DE) ((float*)ws)[WS_ACC_OFF + t] = 0.f;
        if (t == DE) ws[WS_DONE_OFF] = 0;
    }
    __syncthreads();
    if (t == 0) ws[WS_CNT_OFF + b] = s_cnt;            // unconditional write
    const int cl = s_cnt < PBCAP ? s_cnt : PBCAP;
    if (t < cl) ws[WS_LIST_OFF + b * PBCAP + t] = s_list[t];
}

__global__ __launch_bounds__(256)
void compute_k(const float* __restrict__ Eemb,
               const float* __restrict__ Remb,
               const float* __restrict__ basis,
               const float* __restrict__ att,
               const int* __restrict__ node_id,
               const int* __restrict__ edge_src,
               const int* __restrict__ edge_type,
               const int* __restrict__ rel_index,
               int* __restrict__ ws,
               float* __restrict__ out) {
    const int t = threadIdx.x;
    const int chunk = blockIdx.x;          // 0..7  (i-chunk)
    const int jslot = blockIdx.y;          // 0..31 (edge slot)
    float* acc = (float*)ws + WS_ACC_OFF;

    __shared__ int s_counts[FBLOCKS];
    __shared__ unsigned long long s_mask[FBLOCKS / 64];
    __shared__ int s_edges[MAXE];
    __shared__ int s_total, s_listed, s_last;
    __shared__ float s_xj[ICHUNK];

    // ---- flatten: parallel count load, ballot non-zero, t0 walks set bits
    const int c = ws[WS_CNT_OFF + t];      // blockDim == FBLOCKS == 256
    s_counts[t] = c;
    const unsigned long long bal = __ballot(c > 0);
    if ((t & 63) == 0) s_mask[t >> 6] = bal;
    __syncthreads();
    if (t == 0) {
        int tot = 0, listed = 0;
        for (int w = 0; w < FBLOCKS / 64; ++w) {
            unsigned long long m = s_mask[w];
            while (m) {
                const int bb = w * 64 + __builtin_ctzll(m);
                m &= m - 1;
                const int cb = s_counts[bb];
                tot += cb;
                const int cl = cb < PBCAP ? cb : PBCAP;
                for (int k = 0; k < cl && listed < MAXE; ++k)
                    s_edges[listed++] = ws[WS_LIST_OFF + bb * PBCAP + k];
            }
        }
        s_total  = tot;
        s_listed = listed;
    }
    __syncthreads();

    const int cnt  = s_listed;
    const int base = chunk * ICHUNK;

    float m = 0.f;
    bool any = false;
    for (int j = jslot; j < cnt; j += MAXJ) {
        const int e   = s_edges[j];
        const int src = edge_src[e];
        const int typ = edge_type[e];
        const int ri  = rel_index[e];
        __syncthreads();                   // protect s_xj from prior-iter readers
        if (t < ICHUNK) {
            const int i = base + t;
            s_xj[t] = (i < DE) ? Eemb[(size_t)node_id[src] * DE + i]
                               : Remb[(size_t)ri * DE + (i - DE)];
        }
        __syncthreads();
        if (t < DE) {
            const float a0 = att[typ * 4 + 0];
            const float a1 = att[typ * 4 + 1];
            const float a2 = att[typ * 4 + 2];
            const float a3 = att[typ * 4 + 3];
            float h0 = 0.f, h1 = 0.f, h2 = 0.f, h3 = 0.f;
            // basis[b][i][o] at (b*IN_DIM + i)*DE + o ; b-stride = 80000
            #pragma unroll 5
            for (int ii = 0; ii < ICHUNK; ++ii) {
                const float xv  = s_xj[ii];
                const int   off = (base + ii) * DE + t;
                h0 += xv * basis[off];
                h1 += xv * basis[off + 80000];
                h2 += xv * basis[off + 160000];
                h3 += xv * basis[off + 240000];
            }
            m += a0 * h0 + a1 * h1 + a2 * h2 + a3 * h3;
            any = true;
        }
    }
    if (any) atomicAdd(&acc[t], m);

    // ---- last-block finalize (no extra dispatch)
    __threadfence();                       // order this thread's acc-add before done-add
    __syncthreads();
    if (t == 0) {
        const int d = atomicAdd(&ws[WS_DONE_OFF], 1);
        s_last = (d == TOTB - 1);
    }
    __syncthreads();
    if (s_last) {
        __threadfence();
        if (t < DE) {
            const float v = atomicAdd(&acc[t], 0.f);   // coherent read-back
            int cdiv = s_total;
            if (cdiv < 1) cdiv = 1;
            out[t] = v / (float)cdiv;
        }
    }
}

extern "C" void kernel_launch(void* const* d_in, const int* in_sizes, int n_in,
                              void* d_out, int out_size, void* d_ws, size_t ws_size,
                              hipStream_t stream) {
    const float* Eemb  = (const float*)d_in[0];
    const float* Remb  = (const float*)d_in[1];
    const float* basis = (const float*)d_in[2];
    const float* att   = (const float*)d_in[3];
    const int* node_id  = (const int*)d_in[4];
    const int* edge_src = (const int*)d_in[5];
    const int* edge_dst = (const int*)d_in[6];
    const int* edge_typ = (const int*)d_in[7];
    const int* rel_idx  = (const int*)d_in[8];
    const int* unseen   = (const int*)d_in[9];
    float* out = (float*)d_out;
    int*   ws  = (int*)d_ws;

    const int n_edges = in_sizes[6];
    const int n4 = n_edges / 4;

    filter_k<<<FBLOCKS, 256, 0, stream>>>((const int4*)edge_dst, edge_dst,
                                          unseen, n4, n_edges, ws);

    dim3 cgrid(NCHUNK, MAXJ);
    compute_k<<<cgrid, 256, 0, stream>>>(Eemb, Remb, basis, att, node_id,
                                         edge_src, edge_typ, rel_idx,
                                         ws, out);
}

// Round 3
// 132.126 us; speedup vs baseline: 1.6417x; 1.0951x over previous
//
#include <hip/hip_runtime.h>

// Problem: output = embeddings[unseen_index] (200 floats). Only edges with
// edge_dst == unseen_index contribute (~8 of 400000 expected).
//
// Round 5: round-2's last-block finalize (__threadfence per block) cost
// ~13 us (fence storm across 8 non-coherent L2s). Eliminate the
// cross-block reduction ALGEBRAICALLY instead:
//   out[o] = (1/cnt) * sum_{b,i} y[b,i] * basis[b,i,o],
//   y[b,i] = sum_e att[edge_type_e, b] * xj_e[i]   (4 x 400, ~8 edges)
// -> partition over o only: 50 blocks x 4 cols, each block computes y
//    redundantly (cheap) and dots it with its column slice of basis.
//    basis is read EXACTLY ONCE (1.28 MB, vs 10.2 MB duplicated before).
//    No atomics, no fences, no finalize node, no memset node.
// Basis loads are issued into registers BEFORE the flatten/y phases so
// their HBM latency hides under that work.

#define DE 200
#define IN_DIM 400
#define NB 4
#define ROWS (NB * IN_DIM)     // 1600
#define FBLOCKS 256
#define PBCAP 64               // per-filter-block match cap
#define MAXE 128               // flattened match cap (expected ~8)
#define CBLOCKS 50             // compute blocks, 4 output cols each
#define CPB 4                  // cols per block
#define KITER (ROWS / 64)      // 25 rows per thread-rowgroup

// ws layout (32-bit words):
// [0 .. 256)    per-filter-block true counts (always written, no memset)
// [1024 .. )    per-block match lists, PBCAP each
#define WS_CNT_OFF  0
#define WS_LIST_OFF 1024

__global__ __launch_bounds__(256)
void filter_k(const int4* __restrict__ edge_dst4,
              const int* __restrict__ edge_dst,
              const int* __restrict__ unseen,
              int n4, int n_edges,
              int* __restrict__ ws) {
    const int b = blockIdx.x;
    const int t = threadIdx.x;
    __shared__ int s_cnt;
    __shared__ int s_list[PBCAP];
    if (t == 0) s_cnt = 0;
    __syncthreads();

    const int u = unseen[0];
    for (int idx = b * blockDim.x + t; idx < n4; idx += FBLOCKS * blockDim.x) {
        const int4 v = edge_dst4[idx];
        const int  e = idx * 4;
        if (v.x == u) { int p = atomicAdd(&s_cnt, 1); if (p < PBCAP) s_list[p] = e;     }
        if (v.y == u) { int p = atomicAdd(&s_cnt, 1); if (p < PBCAP) s_list[p] = e + 1; }
        if (v.z == u) { int p = atomicAdd(&s_cnt, 1); if (p < PBCAP) s_list[p] = e + 2; }
        if (v.w == u) { int p = atomicAdd(&s_cnt, 1); if (p < PBCAP) s_list[p] = e + 3; }
    }
    if (b == 0 && t < (n_edges & 3)) {
        const int e = n4 * 4 + t;
        if (edge_dst[e] == u) { int p = atomicAdd(&s_cnt, 1); if (p < PBCAP) s_list[p] = e; }
    }
    __syncthreads();
    if (t == 0) ws[WS_CNT_OFF + b] = s_cnt;            // unconditional write
    const int cl = s_cnt < PBCAP ? s_cnt : PBCAP;
    if (t < cl) ws[WS_LIST_OFF + b * PBCAP + t] = s_list[t];
}

__global__ __launch_bounds__(256)
void compute_k(const float* __restrict__ Eemb,
               const float* __restrict__ Remb,
               const float* __restrict__ basis,
               const float* __restrict__ att,
               const int* __restrict__ node_id,
               const int* __restrict__ edge_src,
               const int* __restrict__ edge_type,
               const int* __restrict__ rel_index,
               const int* __restrict__ ws,
               float* __restrict__ out) {
    const int t  = threadIdx.x;
    const int c  = t & 3;                  // col within block
    const int rg = t >> 2;                 // row group 0..63
    const int o  = blockIdx.x * CPB + c;   // output column

    // Issue this thread's 25 basis loads NOW; latency hides under
    // the flatten + y phases below (first use is after the LDS phases).
    float rv[KITER];
    #pragma unroll
    for (int k = 0; k < KITER; ++k)
        rv[k] = basis[(size_t)(rg + 64 * k) * DE + o];

    __shared__ int   s_counts[FBLOCKS];
    __shared__ unsigned long long s_mask[FBLOCKS / 64];
    __shared__ int   s_edges[MAXE];
    __shared__ int   s_srcrow[MAXE];
    __shared__ int   s_ri[MAXE];
    __shared__ float s_att[MAXE][NB];
    __shared__ int   s_total, s_listed;
    __shared__ float s_y[ROWS];            // y[b*400 + i]
    __shared__ float s_part[256];

    // ---- flatten per-filter-block lists (parallel count load + ballot)
    const int cv = ws[WS_CNT_OFF + t];
    s_counts[t] = cv;
    const unsigned long long bal = __ballot(cv > 0);
    if ((t & 63) == 0) s_mask[t >> 6] = bal;
    __syncthreads();
    if (t == 0) {
        int tot = 0, listed = 0;
        for (int w = 0; w < FBLOCKS / 64; ++w) {
            unsigned long long m = s_mask[w];
            while (m) {
                const int bb = w * 64 + __builtin_ctzll(m);
                m &= m - 1;
                const int cb = s_counts[bb];
                tot += cb;
                const int cl = cb < PBCAP ? cb : PBCAP;
                for (int k = 0; k < cl && listed < MAXE; ++k)
                    s_edges[listed++] = ws[WS_LIST_OFF + bb * PBCAP + k];
            }
        }
        s_total  = tot;
        s_listed = listed;
    }
    __syncthreads();
    const int cnt = s_listed;

    // ---- per-edge metadata (parallel over the ~8 edges)
    if (t < cnt) {
        const int e = s_edges[t];
        s_srcrow[t] = node_id[edge_src[e]];
        s_ri[t]     = rel_index[e];
        const int typ = edge_type[e];
        #pragma unroll
        for (int b = 0; b < NB; ++b) s_att[t][b] = att[typ * NB + b];
    }
    __syncthreads();

    // ---- y[b,i] = sum_e att[e,b] * xj_e[i]
    for (int i = t; i < IN_DIM; i += 256) {
        float y0 = 0.f, y1 = 0.f, y2 = 0.f, y3 = 0.f;
        for (int j = 0; j < cnt; ++j) {
            const float xv = (i < DE)
                ? Eemb[(size_t)s_srcrow[j] * DE + i]
                : Remb[(size_t)s_ri[j] * DE + (i - DE)];
            y0 += s_att[j][0] * xv;
            y1 += s_att[j][1] * xv;
            y2 += s_att[j][2] * xv;
            y3 += s_att[j][3] * xv;
        }
        s_y[0 * IN_DIM + i] = y0;
        s_y[1 * IN_DIM + i] = y1;
        s_y[2 * IN_DIM + i] = y2;
        s_y[3 * IN_DIM + i] = y3;
    }
    __syncthreads();

    // ---- column dot: acc = sum_k rv[k] * y[rg + 64k]
    float acc = 0.f;
    #pragma unroll
    for (int k = 0; k < KITER; ++k)
        acc += rv[k] * s_y[rg + 64 * k];   // group-of-4 same addr -> broadcast

    // ---- reduce 64 row-groups per column (offsets multiple of 4 keep c)
    s_part[t] = acc;
    __syncthreads();
    #pragma unroll
    for (int off = 128; off >= 4; off >>= 1) {
        if (t < off) s_part[t] += s_part[t + off];
        __syncthreads();
    }
    if (t < CPB) {
        int cd = s_total;
        if (cd < 1) cd = 1;
        out[blockIdx.x * CPB + t] = s_part[t] / (float)cd;
    }
}

extern "C" void kernel_launch(void* const* d_in, const int* in_sizes, int n_in,
                              void* d_out, int out_size, void* d_ws, size_t ws_size,
                              hipStream_t stream) {
    const float* Eemb  = (const float*)d_in[0];
    const float* Remb  = (const float*)d_in[1];
    const float* basis = (const float*)d_in[2];
    const float* att   = (const float*)d_in[3];
    const int* node_id  = (const int*)d_in[4];
    const int* edge_src = (const int*)d_in[5];
    const int* edge_dst = (const int*)d_in[6];
    const int* edge_typ = (const int*)d_in[7];
    const int* rel_idx  = (const int*)d_in[8];
    const int* unseen   = (const int*)d_in[9];
    float* out = (float*)d_out;
    int*   ws  = (int*)d_ws;

    const int n_edges = in_sizes[6];
    const int n4 = n_edges / 4;

    filter_k<<<FBLOCKS, 256, 0, stream>>>((const int4*)edge_dst, edge_dst,
                                          unseen, n4, n_edges, ws);

    compute_k<<<CBLOCKS, 256, 0, stream>>>(Eemb, Remb, basis, att, node_id,
                                           edge_src, edge_typ, rel_idx,
                                           ws, out);
}